// Round 17
// baseline (1623.692 us; speedup 1.0000x reference)
//
#include <hip/hip_runtime.h>
#include <math.h>

#define N_DST   32768
#define N_EDGE  524288
#define LN_EPS  1e-5f

typedef __attribute__((ext_vector_type(8))) short short8b;   // 8 bf16 (4 VGPR)
typedef __attribute__((ext_vector_type(4))) short short4b;   // 4 bf16 (8 B)
typedef __attribute__((ext_vector_type(4))) float f32x4;

static __device__ __forceinline__ unsigned short f2bf(float f) {
    unsigned u = __float_as_uint(f);
    u += 0x7fff + ((u >> 16) & 1);          // round-to-nearest-even
    return (unsigned short)(u >> 16);
}
static __device__ __forceinline__ float bf2f(unsigned short s) {
    return __uint_as_float(((unsigned)s) << 16);
}

// ---------- prep: K+V weights -> MFMA B-frag order (padded K'=384), zq, wout^T ----------
// Wvp[part][kc][n][l][jj], part 0=K rows 0..99 of wkv_w, part 1=V rows 100..199.
__global__ void k_prep(const float* __restrict__ wkv_w, const float* __restrict__ wq_w,
                       const float* __restrict__ wq_b, const float* __restrict__ time_b,
                       const float* __restrict__ wout_w,
                       unsigned short* __restrict__ Wvp, float* __restrict__ zq,
                       float* __restrict__ wout_t) {
    int idx = blockIdx.x * 256 + threadIdx.x;
    if (idx < 86016) {
        int part = idx / 43008, r2 = idx % 43008;
        int jj = r2 & 7, l = (r2 >> 3) & 63, n = (r2 >> 9) % 7, kc = r2 / 3584;
        int c = n * 16 + (l & 15);
        int kp = kc * 32 + ((l >> 4) << 3) + jj;
        int region = kp >> 7, ridx = kp & 127;
        float v = (c < 100 && ridx < 100)
                  ? wkv_w[(size_t)(part * 100 + c) * 300 + region * 100 + ridx] : 0.f;
        Wvp[idx] = f2bf(v);
    } else if (idx < 86116) {
        int o = idx - 86016;
        float acc = wq_b[o];
        for (int j = 0; j < 100; ++j)
            acc += cosf(time_b[j]) * wq_w[o * 200 + 100 + j];
        zq[o] = acc;
    } else if (idx < 106116) {
        int r = idx - 86116;                    // wout_t[i][o] = wout_w[o][i]
        wout_t[r] = wout_w[(size_t)(r % 100) * 200 + r / 100];
    }
}

// ---------- CSR offsets via binary search over sorted edge_dst ----------
__global__ void k_offsets(const int* __restrict__ dst, int* __restrict__ off) {
    int n = blockIdx.x * 256 + threadIdx.x;
    if (n > N_DST) return;
    int lo = 0, hi = N_EDGE;
    while (lo < hi) {
        int mid = (lo + hi) >> 1;
        if (dst[mid] < n) lo = mid + 1; else hi = mid;
    }
    off[n] = lo;
}

// ---------- Q = dst_h @ wq_w[:, :100].T + zq : 16 nodes/block ----------
__global__ __launch_bounds__(128) void k_q(const float* __restrict__ dst_h,
                                           const float* __restrict__ wq_w,
                                           const float* __restrict__ zq,
                                           float* __restrict__ Q) {
    __shared__ float Ds[16][100];
    int n0 = blockIdx.x * 16, t = threadIdx.x;
    for (int idx = t; idx < 1600; idx += 128)
        Ds[idx / 100][idx % 100] = dst_h[(size_t)n0 * 100 + idx];
    __syncthreads();
    if (t < 100) {
        float z = zq[t];
        float acc[16];
        #pragma unroll
        for (int n = 0; n < 16; ++n) acc[n] = z;
        const float* __restrict__ wr = wq_w + t * 200;
        for (int i = 0; i < 100; ++i) {
            float w = wr[i];
            #pragma unroll
            for (int n = 0; n < 16; ++n) acc[n] = fmaf(Ds[n][i], w, acc[n]);
        }
        #pragma unroll
        for (int n = 0; n < 16; ++n) Q[(size_t)(n0 + n) * 100 + t] = acc[n];
    }
}

// ---------- k_edge: PURE dual GEMM. K and V both -> bf16 buffers. No gather/epilogue ----------
// Round-15 frame (best known): 21 KB LDS slabs (3 kc), af[12] shared across parts.
__global__ __launch_bounds__(256, 1) void k_edge(
        const float* __restrict__ src_h, const float* __restrict__ efeat,
        const float* __restrict__ td,
        const float* __restrict__ time_w, const float* __restrict__ time_b,
        const unsigned short* __restrict__ Wvp, const float* __restrict__ wkv_b,
        unsigned short* __restrict__ Kb, unsigned short* __restrict__ Vb) {
    __shared__ alignas(16) unsigned short Wlds[10752];   // 21 KiB slab: 3 kc x 7 x 64 x 8
    const int t = threadIdx.x, lane = t & 63;
    const int g = blockIdx.x * 4 + (t >> 6);             // wave: group g (16 edges)
    const int col = lane & 15, slice = lane >> 4;
    const int r0 = g * 16 + col;
    const float td0 = td[r0];
    const float4 z4 = make_float4(0.f, 0.f, 0.f, 0.f);

    // ---- Phase A: issue ALL src/efeat staging loads ----
    float4 s[16];
    #pragma unroll
    for (int kc = 0; kc < 8; ++kc) {
        const float* __restrict__ base = (kc < 4) ? src_h : efeat;
        const int idx0 = (kc & 3) * 32 + slice * 8;
        const float* b0 = base + (size_t)r0 * 100 + idx0;
        s[kc * 2]     = (idx0 <= 96) ? *(const float4*)b0       : z4;
        s[kc * 2 + 1] = (idx0 <= 88) ? *(const float4*)(b0 + 4) : z4;
    }
    // ---- Phase B: time features (VALU; overlaps staging) ----
    short8b af[12];
    #pragma unroll
    for (int kc = 8; kc < 12; ++kc) {
        const int idx0 = (kc & 3) * 32 + slice * 8;
        float4 xa = z4, xb = z4;
        if (idx0 <= 96) {
            float4 tw = *(const float4*)(time_w + idx0);
            float4 tb = *(const float4*)(time_b + idx0);
            xa.x = __cosf(fmaf(td0, tw.x, tb.x)); xa.y = __cosf(fmaf(td0, tw.y, tb.y));
            xa.z = __cosf(fmaf(td0, tw.z, tb.z)); xa.w = __cosf(fmaf(td0, tw.w, tb.w));
            if (idx0 <= 88) {
                float4 tw2 = *(const float4*)(time_w + idx0 + 4);
                float4 tb2 = *(const float4*)(time_b + idx0 + 4);
                xb.x = __cosf(fmaf(td0, tw2.x, tb2.x)); xb.y = __cosf(fmaf(td0, tw2.y, tb2.y));
                xb.z = __cosf(fmaf(td0, tw2.z, tb2.z)); xb.w = __cosf(fmaf(td0, tw2.w, tb2.w));
            }
        }
        short8b a;
        a[0] = (short)f2bf(xa.x); a[1] = (short)f2bf(xa.y);
        a[2] = (short)f2bf(xa.z); a[3] = (short)f2bf(xa.w);
        a[4] = (short)f2bf(xb.x); a[5] = (short)f2bf(xb.y);
        a[6] = (short)f2bf(xb.z); a[7] = (short)f2bf(xb.w);
        af[kc] = a;
    }
    // ---- Phase C: pack src/efeat A-frags ----
    #pragma unroll
    for (int kc = 0; kc < 8; ++kc) {
        float4 xa = s[kc * 2], xb = s[kc * 2 + 1];
        short8b a;
        a[0] = (short)f2bf(xa.x); a[1] = (short)f2bf(xa.y);
        a[2] = (short)f2bf(xa.z); a[3] = (short)f2bf(xa.w);
        a[4] = (short)f2bf(xb.x); a[5] = (short)f2bf(xb.y);
        a[6] = (short)f2bf(xb.z); a[7] = (short)f2bf(xb.w);
        af[kc] = a;
    }

    f32x4 acc[7];
    const int re0 = g * 16 + (slice << 2);

    // ================= PART 0: K -> Kb (bf16) =================
    #pragma unroll
    for (int n = 0; n < 7; ++n) {
        int cl = n * 16 + col;
        float b = (cl < 100) ? wkv_b[cl] : 0.f;         // K bias included
        acc[n] = (f32x4){b, b, b, b};
    }
    #pragma unroll
    for (int slab = 0; slab < 4; ++slab) {
        {   // stage 3-kc slab: 1344 float4 = 5*256 + 64
            const float4* __restrict__ wsrc = (const float4*)Wvp + slab * 1344;
            float4* __restrict__ wdst = (float4*)Wlds;
            #pragma unroll
            for (int i = 0; i < 5; ++i) wdst[i * 256 + t] = wsrc[i * 256 + t];
            if (t < 64) wdst[1280 + t] = wsrc[1280 + t];
        }
        __syncthreads();
        #pragma unroll
        for (int kl = 0; kl < 3; ++kl) {
            const int kc = slab * 3 + kl;
            #pragma unroll
            for (int n = 0; n < 7; ++n) {
                short8b w = *(const short8b*)(&Wlds[(size_t)((kl * 7 + n) * 64 + lane) * 8]);
                acc[n] = __builtin_amdgcn_mfma_f32_16x16x32_bf16(af[kc], w, acc[n], 0, 0, 0);
            }
        }
        __syncthreads();
    }
    #pragma unroll
    for (int n = 0; n < 7; ++n) {
        int cl = n * 16 + col;
        if (cl < 100) {
            #pragma unroll
            for (int r = 0; r < 4; ++r)
                Kb[(size_t)(re0 + r) * 100 + cl] = f2bf(acc[n][r]);
        }
    }

    // ================= PART 1: V -> Vb (bf16) =================
    #pragma unroll
    for (int n = 0; n < 7; ++n) {
        int cl = n * 16 + col;
        float b = (cl < 100) ? wkv_b[100 + cl] : 0.f;
        acc[n] = (f32x4){b, b, b, b};
    }
    #pragma unroll
    for (int slab = 0; slab < 4; ++slab) {
        {
            const float4* __restrict__ wsrc = (const float4*)Wvp + (4 + slab) * 1344;
            float4* __restrict__ wdst = (float4*)Wlds;
            #pragma unroll
            for (int i = 0; i < 5; ++i) wdst[i * 256 + t] = wsrc[i * 256 + t];
            if (t < 64) wdst[1280 + t] = wsrc[1280 + t];
        }
        __syncthreads();
        #pragma unroll
        for (int kl = 0; kl < 3; ++kl) {
            const int kc = slab * 3 + kl;
            #pragma unroll
            for (int n = 0; n < 7; ++n) {
                short8b w = *(const short8b*)(&Wlds[(size_t)((kl * 7 + n) * 64 + lane) * 8]);
                acc[n] = __builtin_amdgcn_mfma_f32_16x16x32_bf16(af[kc], w, acc[n], 0, 0, 0);
            }
        }
        __syncthreads();
    }
    #pragma unroll
    for (int n = 0; n < 7; ++n) {
        int cl = n * 16 + col;
        if (cl < 100) {
            #pragma unroll
            for (int r = 0; r < 4; ++r)
                Vb[(size_t)(re0 + r) * 100 + cl] = f2bf(acc[n][r]);
        }
    }
}

// ---------- k_soft: logits (Q.K per node, Q loaded once) + softmax + weighted V ----------
__global__ __launch_bounds__(256) void k_soft(const float* __restrict__ Q,
                                              const unsigned short* __restrict__ Kb,
                                              float2* attn,
                                              const unsigned short* __restrict__ V,
                                              const int* __restrict__ off,
                                              float* __restrict__ agg) {
    const int lane = threadIdx.x & 63;
    const int n = blockIdx.x * 4 + (threadIdx.x >> 6);
    const int r0 = off[n], cnt = off[n + 1] - r0;
    float* __restrict__ aout = agg + (size_t)n * 100;
    if (cnt <= 0) {
        aout[lane] = 0.f;
        if (lane < 36) aout[64 + lane] = 0.f;
        return;
    }

    // ---- phase 0: logits. 16 lanes per edge, 4 edges per iteration ----
    {
        const int g16 = lane & 15, eg = lane >> 4;
        const int c0 = g16 * 8;
        float q8[8];
        {
            const float* __restrict__ qn = Q + (size_t)n * 100;
            #pragma unroll
            for (int j = 0; j < 8; ++j) {
                int c = c0 + j;
                q8[j] = (c < 100) ? qn[c] : 0.f;
            }
        }
        for (int base = 0; base < cnt; base += 4) {
            int e = base + eg;
            float p0 = 0.f, p1 = 0.f;
            if (e < cnt) {
                const unsigned short* __restrict__ kr = Kb + (size_t)(r0 + e) * 100 + c0;
                unsigned short kraw[8] = {0, 0, 0, 0, 0, 0, 0, 0};
                if (g16 < 12) {
                    short4b ka = *(const short4b*)kr;
                    short4b kb2 = *(const short4b*)(kr + 4);
                    kraw[0] = ka[0]; kraw[1] = ka[1]; kraw[2] = ka[2]; kraw[3] = ka[3];
                    kraw[4] = kb2[0]; kraw[5] = kb2[1]; kraw[6] = kb2[2]; kraw[7] = kb2[3];
                } else if (g16 == 12) {
                    short4b ka = *(const short4b*)kr;
                    kraw[0] = ka[0]; kraw[1] = ka[1]; kraw[2] = ka[2]; kraw[3] = ka[3];
                }
                #pragma unroll
                for (int j = 0; j < 8; ++j) {
                    float term = bf2f(kraw[j]) * q8[j];
                    if (c0 + j < 50) p0 += term; else p1 += term;
                }
            }
            #pragma unroll
            for (int sh = 1; sh < 16; sh <<= 1) {
                p0 += __shfl_xor(p0, sh);
                p1 += __shfl_xor(p1, sh);
            }
            if (g16 == 0 && e < cnt) {
                attn[r0 + e] = make_float2(p0 > 0.f ? p0 : 0.2f * p0,
                                           p1 > 0.f ? p1 : 0.2f * p1);
            }
        }
        __threadfence();   // per-wave: make our attn stores visible to our later loads
    }

    float m0 = -1e30f, m1 = -1e30f;
    for (int i = lane; i < cnt; i += 64) {
        float2 a = attn[r0 + i];
        m0 = fmaxf(m0, a.x); m1 = fmaxf(m1, a.y);
    }
    #pragma unroll
    for (int s = 1; s < 64; s <<= 1) {
        m0 = fmaxf(m0, __shfl_xor(m0, s));
        m1 = fmaxf(m1, __shfl_xor(m1, s));
    }
    float s0 = 0.f, s1 = 0.f;
    for (int i = lane; i < cnt; i += 64) {
        float2 a = attn[r0 + i];
        s0 += __expf(a.x - m0); s1 += __expf(a.y - m1);
    }
    #pragma unroll
    for (int s = 1; s < 64; s <<= 1) { s0 += __shfl_xor(s0, s); s1 += __shfl_xor(s1, s); }
    const float inv0 = 1.f / s0, inv1 = 1.f / s1;

    float aa0 = 0.f, aa1 = 0.f, aa2 = 0.f, aa3 = 0.f;
    float ab0 = 0.f, ab1 = 0.f, ab2 = 0.f, ab3 = 0.f;
    for (int base = 0; base < cnt; base += 64) {
        int i = base + lane;
        float e0 = 0.f, e1 = 0.f;
        if (i < cnt) {
            float2 a = attn[r0 + i];
            e0 = __expf(a.x - m0) * inv0;
            e1 = __expf(a.y - m1) * inv1;
        }
        int lim = min(64, cnt - base);
        const unsigned short* __restrict__ vrow = V + (size_t)(r0 + base) * 100;
        int j = 0;
        for (; j + 4 <= lim; j += 4) {
            float q00 = __shfl(e0, j),     q10 = __shfl(e1, j);
            float q01 = __shfl(e0, j + 1), q11 = __shfl(e1, j + 1);
            float q02 = __shfl(e0, j + 2), q12 = __shfl(e1, j + 2);
            float q03 = __shfl(e0, j + 3), q13 = __shfl(e1, j + 3);
            const unsigned short* w0 = vrow + (size_t)j * 100;
            float pa0 = (lane < 50) ? q00 : q10;
            float pa1 = (lane < 50) ? q01 : q11;
            float pa2 = (lane < 50) ? q02 : q12;
            float pa3 = (lane < 50) ? q03 : q13;
            aa0 = fmaf(pa0, bf2f(w0[lane]),       aa0);
            aa1 = fmaf(pa1, bf2f(w0[100 + lane]), aa1);
            aa2 = fmaf(pa2, bf2f(w0[200 + lane]), aa2);
            aa3 = fmaf(pa3, bf2f(w0[300 + lane]), aa3);
            if (lane < 36) {
                ab0 = fmaf(q10, bf2f(w0[64 + lane]),  ab0);
                ab1 = fmaf(q11, bf2f(w0[164 + lane]), ab1);
                ab2 = fmaf(q12, bf2f(w0[264 + lane]), ab2);
                ab3 = fmaf(q13, bf2f(w0[364 + lane]), ab3);
            }
        }
        for (; j < lim; ++j) {
            float q0 = __shfl(e0, j), q1 = __shfl(e1, j);
            const unsigned short* w0 = vrow + (size_t)j * 100;
            float pa = (lane < 50) ? q0 : q1;
            aa0 = fmaf(pa, bf2f(w0[lane]), aa0);
            if (lane < 36) ab0 = fmaf(q1, bf2f(w0[64 + lane]), ab0);
        }
    }
    aout[lane] = (aa0 + aa1) + (aa2 + aa3);
    if (lane < 36) aout[64 + lane] = (ab0 + ab1) + (ab2 + ab3);
}

// ---------- out proj + relu + layernorm: 8 nodes/block, coalesced wout_t ----------
__global__ __launch_bounds__(128) void k_out(const float* __restrict__ agg,
                                             const float* __restrict__ dst_h,
                                             const float* __restrict__ wout_t,
                                             const float* __restrict__ wout_b,
                                             const float* __restrict__ ln_g,
                                             const float* __restrict__ ln_b,
                                             float* __restrict__ out) {
    __shared__ float Fs[8][200];
    __shared__ float red[8][128];
    const int n0 = blockIdx.x * 8, t = threadIdx.x;
    for (int idx = t; idx < 1600; idx += 128) {
        int n = idx / 200, i = idx % 200;
        Fs[n][i] = (i < 100) ? agg[(size_t)(n0 + n) * 100 + i]
                             : dst_h[(size_t)(n0 + n) * 100 + (i - 100)];
    }
    __syncthreads();
    float v[8] = {0.f, 0.f, 0.f, 0.f, 0.f, 0.f, 0.f, 0.f};
    if (t < 100) {
        float b = wout_b[t];
        #pragma unroll
        for (int n = 0; n < 8; ++n) v[n] = b;
        for (int i = 0; i < 200; ++i) {
            float w = wout_t[i * 100 + t];
            #pragma unroll
            for (int n = 0; n < 8; ++n) v[n] = fmaf(Fs[n][i], w, v[n]);
        }
        #pragma unroll
        for (int n = 0; n < 8; ++n) v[n] = fmaxf(v[n], 0.f);
    }
    #pragma unroll
    for (int n = 0; n < 8; ++n) red[n][t] = (t < 100) ? v[n] : 0.f;
    __syncthreads();
    for (int s = 64; s > 0; s >>= 1) {
        if (t < s) {
            #pragma unroll
            for (int n = 0; n < 8; ++n) red[n][t] += red[n][t + s];
        }
        __syncthreads();
    }
    float mu[8];
    #pragma unroll
    for (int n = 0; n < 8; ++n) mu[n] = red[n][0] * 0.01f;
    __syncthreads();
    #pragma unroll
    for (int n = 0; n < 8; ++n) {
        float dv = (t < 100) ? (v[n] - mu[n]) : 0.f;
        red[n][t] = dv * dv;
    }
    __syncthreads();
    for (int s = 64; s > 0; s >>= 1) {
        if (t < s) {
            #pragma unroll
            for (int n = 0; n < 8; ++n) red[n][t] += red[n][t + s];
        }
        __syncthreads();
    }
    if (t < 100) {
        #pragma unroll
        for (int n = 0; n < 8; ++n) {
            float var = red[n][0] * 0.01f;
            out[(size_t)(n0 + n) * 100 + t] =
                (v[n] - mu[n]) * rsqrtf(var + LN_EPS) * ln_g[t] + ln_b[t];
        }
    }
}

extern "C" void kernel_launch(void* const* d_in, const int* in_sizes, int n_in,
                              void* d_out, int out_size, void* d_ws, size_t ws_size,
                              hipStream_t stream) {
    const float* dst_h   = (const float*)d_in[0];
    const float* src_h   = (const float*)d_in[1];
    const float* efeat   = (const float*)d_in[2];
    const float* td      = (const float*)d_in[3];
    const int*   edst    = (const int*)  d_in[4];
    const float* time_w  = (const float*)d_in[5];
    const float* time_b  = (const float*)d_in[6];
    const float* wq_w    = (const float*)d_in[7];
    const float* wq_b    = (const float*)d_in[8];
    const float* wkv_w   = (const float*)d_in[9];
    const float* wkv_b   = (const float*)d_in[10];
    const float* wout_w  = (const float*)d_in[11];
    const float* wout_b  = (const float*)d_in[12];
    const float* ln_g    = (const float*)d_in[13];
    const float* ln_b    = (const float*)d_in[14];
    float* out = (float*)d_out;

    char* ws = (char*)d_ws;
    size_t off = 0;
    auto carve = [&](size_t bytes) { char* p = ws + off; off = (off + bytes + 255) & ~(size_t)255; return p; };
    float*          Q     = (float*)carve((size_t)N_DST * 100 * 4);
    float2*         attn  = (float2*)carve((size_t)N_EDGE * 2 * 4);
    unsigned short* Kb    = (unsigned short*)carve((size_t)N_EDGE * 100 * 2);
    unsigned short* Vb    = (unsigned short*)carve((size_t)N_EDGE * 100 * 2);
    float*          agg   = (float*)carve((size_t)N_DST * 100 * 4);
    unsigned short* Wvp   = (unsigned short*)carve(86016 * 2);
    float*          zq    = (float*)carve(100 * 4);
    float*          woutT = (float*)carve(20000 * 4);
    int*            offs  = (int*)carve((size_t)(N_DST + 1) * 4);

    k_prep<<<(106116 + 255) / 256, 256, 0, stream>>>(wkv_w, wq_w, wq_b, time_b, wout_w,
                                                     Wvp, zq, woutT);
    k_offsets<<<(N_DST + 1 + 255) / 256, 256, 0, stream>>>(edst, offs);
    k_q<<<N_DST / 16, 128, 0, stream>>>(dst_h, wq_w, zq, Q);
    k_edge<<<N_EDGE / 64, 256, 0, stream>>>(src_h, efeat, td, time_w, time_b,
                                            Wvp, wkv_b, Kb, Vb);
    k_soft<<<N_DST / 4, 256, 0, stream>>>(Q, Kb, attn, Vb, offs, agg);
    k_out<<<N_DST / 8, 128, 0, stream>>>(agg, dst_h, woutT, wout_b, ln_g, ln_b, out);
}

// Round 18
// 434.513 us; speedup vs baseline: 3.7368x; 3.7368x over previous
//
#include <hip/hip_runtime.h>
#include <math.h>

#define N_DST   32768
#define N_EDGE  524288
#define LN_EPS  1e-5f

typedef __attribute__((ext_vector_type(8))) short short8b;   // 8 bf16 (4 VGPR)
typedef __attribute__((ext_vector_type(4))) short short4b;   // 4 bf16 (8 B)
typedef __attribute__((ext_vector_type(4))) float f32x4;

static __device__ __forceinline__ unsigned short f2bf(float f) {
    unsigned u = __float_as_uint(f);
    u += 0x7fff + ((u >> 16) & 1);          // round-to-nearest-even
    return (unsigned short)(u >> 16);
}
static __device__ __forceinline__ float bf2f(unsigned short s) {
    return __uint_as_float(((unsigned)s) << 16);
}

// ---------- prep: K+V weights -> MFMA B-frag order (padded K'=384), zq, wout^T ----------
// Wvp[part][kc][n][l][jj], part 0=K rows 0..99 of wkv_w, part 1=V rows 100..199.
__global__ void k_prep(const float* __restrict__ wkv_w, const float* __restrict__ wq_w,
                       const float* __restrict__ wq_b, const float* __restrict__ time_b,
                       const float* __restrict__ wout_w,
                       unsigned short* __restrict__ Wvp, float* __restrict__ zq,
                       float* __restrict__ wout_t) {
    int idx = blockIdx.x * 256 + threadIdx.x;
    if (idx < 86016) {
        int part = idx / 43008, r2 = idx % 43008;
        int jj = r2 & 7, l = (r2 >> 3) & 63, n = (r2 >> 9) % 7, kc = r2 / 3584;
        int c = n * 16 + (l & 15);
        int kp = kc * 32 + ((l >> 4) << 3) + jj;
        int region = kp >> 7, ridx = kp & 127;
        float v = (c < 100 && ridx < 100)
                  ? wkv_w[(size_t)(part * 100 + c) * 300 + region * 100 + ridx] : 0.f;
        Wvp[idx] = f2bf(v);
    } else if (idx < 86116) {
        int o = idx - 86016;
        float acc = wq_b[o];
        for (int j = 0; j < 100; ++j)
            acc += cosf(time_b[j]) * wq_w[o * 200 + 100 + j];
        zq[o] = acc;
    } else if (idx < 106116) {
        int r = idx - 86116;                    // wout_t[i][o] = wout_w[o][i]
        wout_t[r] = wout_w[(size_t)(r % 100) * 200 + r / 100];
    }
}

// ---------- CSR offsets via binary search over sorted edge_dst ----------
__global__ void k_offsets(const int* __restrict__ dst, int* __restrict__ off) {
    int n = blockIdx.x * 256 + threadIdx.x;
    if (n > N_DST) return;
    int lo = 0, hi = N_EDGE;
    while (lo < hi) {
        int mid = (lo + hi) >> 1;
        if (dst[mid] < n) lo = mid + 1; else hi = mid;
    }
    off[n] = lo;
}

// ---------- Q = dst_h @ wq_w[:, :100].T + zq : 16 nodes/block ----------
__global__ __launch_bounds__(128) void k_q(const float* __restrict__ dst_h,
                                           const float* __restrict__ wq_w,
                                           const float* __restrict__ zq,
                                           float* __restrict__ Q) {
    __shared__ float Ds[16][100];
    int n0 = blockIdx.x * 16, t = threadIdx.x;
    for (int idx = t; idx < 1600; idx += 128)
        Ds[idx / 100][idx % 100] = dst_h[(size_t)n0 * 100 + idx];
    __syncthreads();
    if (t < 100) {
        float z = zq[t];
        float acc[16];
        #pragma unroll
        for (int n = 0; n < 16; ++n) acc[n] = z;
        const float* __restrict__ wr = wq_w + t * 200;
        for (int i = 0; i < 100; ++i) {
            float w = wr[i];
            #pragma unroll
            for (int n = 0; n < 16; ++n) acc[n] = fmaf(Ds[n][i], w, acc[n]);
        }
        #pragma unroll
        for (int n = 0; n < 16; ++n) Q[(size_t)(n0 + n) * 100 + t] = acc[n];
    }
}

// ---------- k_edge: PURE dual GEMM. K and V both -> bf16 buffers. No gather/epilogue ----------
__global__ __launch_bounds__(256, 1) void k_edge(
        const float* __restrict__ src_h, const float* __restrict__ efeat,
        const float* __restrict__ td,
        const float* __restrict__ time_w, const float* __restrict__ time_b,
        const unsigned short* __restrict__ Wvp, const float* __restrict__ wkv_b,
        unsigned short* __restrict__ Kb, unsigned short* __restrict__ Vb) {
    __shared__ alignas(16) unsigned short Wlds[10752];   // 21 KiB slab: 3 kc x 7 x 64 x 8
    const int t = threadIdx.x, lane = t & 63;
    const int g = blockIdx.x * 4 + (t >> 6);             // wave: group g (16 edges)
    const int col = lane & 15, slice = lane >> 4;
    const int r0 = g * 16 + col;
    const float td0 = td[r0];
    const float4 z4 = make_float4(0.f, 0.f, 0.f, 0.f);

    // ---- Phase A: issue ALL src/efeat staging loads ----
    float4 s[16];
    #pragma unroll
    for (int kc = 0; kc < 8; ++kc) {
        const float* __restrict__ base = (kc < 4) ? src_h : efeat;
        const int idx0 = (kc & 3) * 32 + slice * 8;
        const float* b0 = base + (size_t)r0 * 100 + idx0;
        s[kc * 2]     = (idx0 <= 96) ? *(const float4*)b0       : z4;
        s[kc * 2 + 1] = (idx0 <= 88) ? *(const float4*)(b0 + 4) : z4;
    }
    // ---- Phase B: time features (VALU; overlaps staging) ----
    short8b af[12];
    #pragma unroll
    for (int kc = 8; kc < 12; ++kc) {
        const int idx0 = (kc & 3) * 32 + slice * 8;
        float4 xa = z4, xb = z4;
        if (idx0 <= 96) {
            float4 tw = *(const float4*)(time_w + idx0);
            float4 tb = *(const float4*)(time_b + idx0);
            xa.x = __cosf(fmaf(td0, tw.x, tb.x)); xa.y = __cosf(fmaf(td0, tw.y, tb.y));
            xa.z = __cosf(fmaf(td0, tw.z, tb.z)); xa.w = __cosf(fmaf(td0, tw.w, tb.w));
            if (idx0 <= 88) {
                float4 tw2 = *(const float4*)(time_w + idx0 + 4);
                float4 tb2 = *(const float4*)(time_b + idx0 + 4);
                xb.x = __cosf(fmaf(td0, tw2.x, tb2.x)); xb.y = __cosf(fmaf(td0, tw2.y, tb2.y));
                xb.z = __cosf(fmaf(td0, tw2.z, tb2.z)); xb.w = __cosf(fmaf(td0, tw2.w, tb2.w));
            }
        }
        short8b a;
        a[0] = (short)f2bf(xa.x); a[1] = (short)f2bf(xa.y);
        a[2] = (short)f2bf(xa.z); a[3] = (short)f2bf(xa.w);
        a[4] = (short)f2bf(xb.x); a[5] = (short)f2bf(xb.y);
        a[6] = (short)f2bf(xb.z); a[7] = (short)f2bf(xb.w);
        af[kc] = a;
    }
    // ---- Phase C: pack src/efeat A-frags ----
    #pragma unroll
    for (int kc = 0; kc < 8; ++kc) {
        float4 xa = s[kc * 2], xb = s[kc * 2 + 1];
        short8b a;
        a[0] = (short)f2bf(xa.x); a[1] = (short)f2bf(xa.y);
        a[2] = (short)f2bf(xa.z); a[3] = (short)f2bf(xa.w);
        a[4] = (short)f2bf(xb.x); a[5] = (short)f2bf(xb.y);
        a[6] = (short)f2bf(xb.z); a[7] = (short)f2bf(xb.w);
        af[kc] = a;
    }

    f32x4 acc[7];
    const int re0 = g * 16 + (slice << 2);

    // ================= PART 0: K -> Kb (bf16) =================
    #pragma unroll
    for (int n = 0; n < 7; ++n) {
        int cl = n * 16 + col;
        float b = (cl < 100) ? wkv_b[cl] : 0.f;         // K bias included
        acc[n] = (f32x4){b, b, b, b};
    }
    #pragma unroll
    for (int slab = 0; slab < 4; ++slab) {
        {   // stage 3-kc slab: 1344 float4 = 5*256 + 64
            const float4* __restrict__ wsrc = (const float4*)Wvp + slab * 1344;
            float4* __restrict__ wdst = (float4*)Wlds;
            #pragma unroll
            for (int i = 0; i < 5; ++i) wdst[i * 256 + t] = wsrc[i * 256 + t];
            if (t < 64) wdst[1280 + t] = wsrc[1280 + t];
        }
        __syncthreads();
        #pragma unroll
        for (int kl = 0; kl < 3; ++kl) {
            const int kc = slab * 3 + kl;
            #pragma unroll
            for (int n = 0; n < 7; ++n) {
                short8b w = *(const short8b*)(&Wlds[(size_t)((kl * 7 + n) * 64 + lane) * 8]);
                acc[n] = __builtin_amdgcn_mfma_f32_16x16x32_bf16(af[kc], w, acc[n], 0, 0, 0);
            }
        }
        __syncthreads();
    }
    #pragma unroll
    for (int n = 0; n < 7; ++n) {
        int cl = n * 16 + col;
        if (cl < 100) {
            #pragma unroll
            for (int r = 0; r < 4; ++r)
                Kb[(size_t)(re0 + r) * 100 + cl] = f2bf(acc[n][r]);
        }
    }

    // ================= PART 1: V -> Vb (bf16) =================
    #pragma unroll
    for (int n = 0; n < 7; ++n) {
        int cl = n * 16 + col;
        float b = (cl < 100) ? wkv_b[100 + cl] : 0.f;
        acc[n] = (f32x4){b, b, b, b};
    }
    #pragma unroll
    for (int slab = 0; slab < 4; ++slab) {
        {
            const float4* __restrict__ wsrc = (const float4*)Wvp + (4 + slab) * 1344;
            float4* __restrict__ wdst = (float4*)Wlds;
            #pragma unroll
            for (int i = 0; i < 5; ++i) wdst[i * 256 + t] = wsrc[i * 256 + t];
            if (t < 64) wdst[1280 + t] = wsrc[1280 + t];
        }
        __syncthreads();
        #pragma unroll
        for (int kl = 0; kl < 3; ++kl) {
            const int kc = slab * 3 + kl;
            #pragma unroll
            for (int n = 0; n < 7; ++n) {
                short8b w = *(const short8b*)(&Wlds[(size_t)((kl * 7 + n) * 64 + lane) * 8]);
                acc[n] = __builtin_amdgcn_mfma_f32_16x16x32_bf16(af[kc], w, acc[n], 0, 0, 0);
            }
        }
        __syncthreads();
    }
    #pragma unroll
    for (int n = 0; n < 7; ++n) {
        int cl = n * 16 + col;
        if (cl < 100) {
            #pragma unroll
            for (int r = 0; r < 4; ++r)
                Vb[(size_t)(re0 + r) * 100 + cl] = f2bf(acc[n][r]);
        }
    }
}

// ---------- k_soft: logits (Q.K per node) + softmax + weighted V ----------
// NO threadfence: producer/consumer are the same wave on the same CU; vmcnt ordering
// (attn is non-restrict) + write-through L1 suffice. The device-scope fence was an
// L2-writeback storm (round 17: 1223us, chip idle).
__global__ __launch_bounds__(256) void k_soft(const float* __restrict__ Q,
                                              const unsigned short* __restrict__ Kb,
                                              float2* attn,
                                              const unsigned short* __restrict__ V,
                                              const int* __restrict__ off,
                                              float* __restrict__ agg) {
    const int lane = threadIdx.x & 63;
    const int n = blockIdx.x * 4 + (threadIdx.x >> 6);
    const int r0 = off[n], cnt = off[n + 1] - r0;
    float* __restrict__ aout = agg + (size_t)n * 100;
    if (cnt <= 0) {
        aout[lane] = 0.f;
        if (lane < 36) aout[64 + lane] = 0.f;
        return;
    }

    // ---- phase 0: logits. 16 lanes per edge, 4 edges per iteration ----
    {
        const int g16 = lane & 15, eg = lane >> 4;
        const int c0 = g16 * 8;
        float q8[8];
        {
            const float* __restrict__ qn = Q + (size_t)n * 100;
            #pragma unroll
            for (int j = 0; j < 8; ++j) {
                int c = c0 + j;
                q8[j] = (c < 100) ? qn[c] : 0.f;
            }
        }
        for (int base = 0; base < cnt; base += 4) {
            int e = base + eg;
            float p0 = 0.f, p1 = 0.f;
            if (e < cnt) {
                const unsigned short* __restrict__ kr = Kb + (size_t)(r0 + e) * 100 + c0;
                unsigned short kraw[8] = {0, 0, 0, 0, 0, 0, 0, 0};
                if (g16 < 12) {
                    short4b ka = *(const short4b*)kr;
                    short4b kb2 = *(const short4b*)(kr + 4);
                    kraw[0] = ka[0]; kraw[1] = ka[1]; kraw[2] = ka[2]; kraw[3] = ka[3];
                    kraw[4] = kb2[0]; kraw[5] = kb2[1]; kraw[6] = kb2[2]; kraw[7] = kb2[3];
                } else if (g16 == 12) {
                    short4b ka = *(const short4b*)kr;
                    kraw[0] = ka[0]; kraw[1] = ka[1]; kraw[2] = ka[2]; kraw[3] = ka[3];
                }
                #pragma unroll
                for (int j = 0; j < 8; ++j) {
                    float term = bf2f(kraw[j]) * q8[j];
                    if (c0 + j < 50) p0 += term; else p1 += term;
                }
            }
            #pragma unroll
            for (int sh = 1; sh < 16; sh <<= 1) {
                p0 += __shfl_xor(p0, sh);
                p1 += __shfl_xor(p1, sh);
            }
            if (g16 == 0 && e < cnt) {
                attn[r0 + e] = make_float2(p0 > 0.f ? p0 : 0.2f * p0,
                                           p1 > 0.f ? p1 : 0.2f * p1);
            }
        }
    }

    float m0 = -1e30f, m1 = -1e30f;
    for (int i = lane; i < cnt; i += 64) {
        float2 a = attn[r0 + i];
        m0 = fmaxf(m0, a.x); m1 = fmaxf(m1, a.y);
    }
    #pragma unroll
    for (int s = 1; s < 64; s <<= 1) {
        m0 = fmaxf(m0, __shfl_xor(m0, s));
        m1 = fmaxf(m1, __shfl_xor(m1, s));
    }
    float s0 = 0.f, s1 = 0.f;
    for (int i = lane; i < cnt; i += 64) {
        float2 a = attn[r0 + i];
        s0 += __expf(a.x - m0); s1 += __expf(a.y - m1);
    }
    #pragma unroll
    for (int s = 1; s < 64; s <<= 1) { s0 += __shfl_xor(s0, s); s1 += __shfl_xor(s1, s); }
    const float inv0 = 1.f / s0, inv1 = 1.f / s1;

    float aa0 = 0.f, aa1 = 0.f, aa2 = 0.f, aa3 = 0.f;
    float ab0 = 0.f, ab1 = 0.f, ab2 = 0.f, ab3 = 0.f;
    for (int base = 0; base < cnt; base += 64) {
        int i = base + lane;
        float e0 = 0.f, e1 = 0.f;
        if (i < cnt) {
            float2 a = attn[r0 + i];
            e0 = __expf(a.x - m0) * inv0;
            e1 = __expf(a.y - m1) * inv1;
        }
        int lim = min(64, cnt - base);
        const unsigned short* __restrict__ vrow = V + (size_t)(r0 + base) * 100;
        int j = 0;
        for (; j + 4 <= lim; j += 4) {
            float q00 = __shfl(e0, j),     q10 = __shfl(e1, j);
            float q01 = __shfl(e0, j + 1), q11 = __shfl(e1, j + 1);
            float q02 = __shfl(e0, j + 2), q12 = __shfl(e1, j + 2);
            float q03 = __shfl(e0, j + 3), q13 = __shfl(e1, j + 3);
            const unsigned short* w0 = vrow + (size_t)j * 100;
            float pa0 = (lane < 50) ? q00 : q10;
            float pa1 = (lane < 50) ? q01 : q11;
            float pa2 = (lane < 50) ? q02 : q12;
            float pa3 = (lane < 50) ? q03 : q13;
            aa0 = fmaf(pa0, bf2f(w0[lane]),       aa0);
            aa1 = fmaf(pa1, bf2f(w0[100 + lane]), aa1);
            aa2 = fmaf(pa2, bf2f(w0[200 + lane]), aa2);
            aa3 = fmaf(pa3, bf2f(w0[300 + lane]), aa3);
            if (lane < 36) {
                ab0 = fmaf(q10, bf2f(w0[64 + lane]),  ab0);
                ab1 = fmaf(q11, bf2f(w0[164 + lane]), ab1);
                ab2 = fmaf(q12, bf2f(w0[264 + lane]), ab2);
                ab3 = fmaf(q13, bf2f(w0[364 + lane]), ab3);
            }
        }
        for (; j < lim; ++j) {
            float q0 = __shfl(e0, j), q1 = __shfl(e1, j);
            const unsigned short* w0 = vrow + (size_t)j * 100;
            float pa = (lane < 50) ? q0 : q1;
            aa0 = fmaf(pa, bf2f(w0[lane]), aa0);
            if (lane < 36) ab0 = fmaf(q1, bf2f(w0[64 + lane]), ab0);
        }
    }
    aout[lane] = (aa0 + aa1) + (aa2 + aa3);
    if (lane < 36) aout[64 + lane] = (ab0 + ab1) + (ab2 + ab3);
}

// ---------- out proj + relu + layernorm: 8 nodes/block, coalesced wout_t ----------
__global__ __launch_bounds__(128) void k_out(const float* __restrict__ agg,
                                             const float* __restrict__ dst_h,
                                             const float* __restrict__ wout_t,
                                             const float* __restrict__ wout_b,
                                             const float* __restrict__ ln_g,
                                             const float* __restrict__ ln_b,
                                             float* __restrict__ out) {
    __shared__ float Fs[8][200];
    __shared__ float red[8][128];
    const int n0 = blockIdx.x * 8, t = threadIdx.x;
    for (int idx = t; idx < 1600; idx += 128) {
        int n = idx / 200, i = idx % 200;
        Fs[n][i] = (i < 100) ? agg[(size_t)(n0 + n) * 100 + i]
                             : dst_h[(size_t)(n0 + n) * 100 + (i - 100)];
    }
    __syncthreads();
    float v[8] = {0.f, 0.f, 0.f, 0.f, 0.f, 0.f, 0.f, 0.f};
    if (t < 100) {
        float b = wout_b[t];
        #pragma unroll
        for (int n = 0; n < 8; ++n) v[n] = b;
        for (int i = 0; i < 200; ++i) {
            float w = wout_t[i * 100 + t];
            #pragma unroll
            for (int n = 0; n < 8; ++n) v[n] = fmaf(Fs[n][i], w, v[n]);
        }
        #pragma unroll
        for (int n = 0; n < 8; ++n) v[n] = fmaxf(v[n], 0.f);
    }
    #pragma unroll
    for (int n = 0; n < 8; ++n) red[n][t] = (t < 100) ? v[n] : 0.f;
    __syncthreads();
    for (int s = 64; s > 0; s >>= 1) {
        if (t < s) {
            #pragma unroll
            for (int n = 0; n < 8; ++n) red[n][t] += red[n][t + s];
        }
        __syncthreads();
    }
    float mu[8];
    #pragma unroll
    for (int n = 0; n < 8; ++n) mu[n] = red[n][0] * 0.01f;
    __syncthreads();
    #pragma unroll
    for (int n = 0; n < 8; ++n) {
        float dv = (t < 100) ? (v[n] - mu[n]) : 0.f;
        red[n][t] = dv * dv;
    }
    __syncthreads();
    for (int s = 64; s > 0; s >>= 1) {
        if (t < s) {
            #pragma unroll
            for (int n = 0; n < 8; ++n) red[n][t] += red[n][t + s];
        }
        __syncthreads();
    }
    if (t < 100) {
        #pragma unroll
        for (int n = 0; n < 8; ++n) {
            float var = red[n][0] * 0.01f;
            out[(size_t)(n0 + n) * 100 + t] =
                (v[n] - mu[n]) * rsqrtf(var + LN_EPS) * ln_g[t] + ln_b[t];
        }
    }
}

extern "C" void kernel_launch(void* const* d_in, const int* in_sizes, int n_in,
                              void* d_out, int out_size, void* d_ws, size_t ws_size,
                              hipStream_t stream) {
    const float* dst_h   = (const float*)d_in[0];
    const float* src_h   = (const float*)d_in[1];
    const float* efeat   = (const float*)d_in[2];
    const float* td      = (const float*)d_in[3];
    const int*   edst    = (const int*)  d_in[4];
    const float* time_w  = (const float*)d_in[5];
    const float* time_b  = (const float*)d_in[6];
    const float* wq_w    = (const float*)d_in[7];
    const float* wq_b    = (const float*)d_in[8];
    const float* wkv_w   = (const float*)d_in[9];
    const float* wkv_b   = (const float*)d_in[10];
    const float* wout_w  = (const float*)d_in[11];
    const float* wout_b  = (const float*)d_in[12];
    const float* ln_g    = (const float*)d_in[13];
    const float* ln_b    = (const float*)d_in[14];
    float* out = (float*)d_out;

    char* ws = (char*)d_ws;
    size_t off = 0;
    auto carve = [&](size_t bytes) { char* p = ws + off; off = (off + bytes + 255) & ~(size_t)255; return p; };
    float*          Q     = (float*)carve((size_t)N_DST * 100 * 4);
    float2*         attn  = (float2*)carve((size_t)N_EDGE * 2 * 4);
    unsigned short* Kb    = (unsigned short*)carve((size_t)N_EDGE * 100 * 2);
    unsigned short* Vb    = (unsigned short*)carve((size_t)N_EDGE * 100 * 2);
    float*          agg   = (float*)carve((size_t)N_DST * 100 * 4);
    unsigned short* Wvp   = (unsigned short*)carve(86016 * 2);
    float*          zq    = (float*)carve(100 * 4);
    float*          woutT = (float*)carve(20000 * 4);
    int*            offs  = (int*)carve((size_t)(N_DST + 1) * 4);

    k_prep<<<(106116 + 255) / 256, 256, 0, stream>>>(wkv_w, wq_w, wq_b, time_b, wout_w,
                                                     Wvp, zq, woutT);
    k_offsets<<<(N_DST + 1 + 255) / 256, 256, 0, stream>>>(edst, offs);
    k_q<<<N_DST / 16, 128, 0, stream>>>(dst_h, wq_w, zq, Q);
    k_edge<<<N_EDGE / 64, 256, 0, stream>>>(src_h, efeat, td, time_w, time_b,
                                            Wvp, wkv_b, Kb, Vb);
    k_soft<<<N_DST / 4, 256, 0, stream>>>(Q, Kb, attn, Vb, offs, agg);
    k_out<<<N_DST / 8, 128, 0, stream>>>(agg, dst_h, woutT, wout_b, ln_g, ln_b, out);
}